// Round 3
// baseline (2341.169 us; speedup 1.0000x reference)
//
#include <hip/hip_runtime.h>

// VQ-VAE nearest-code lookup: MFMA filter (code-granular) + coalesced fp32 refine.
// N=65536 tokens, K=1024 codes, D=256, fp32 in/out.
// out layout (flat f32): values[N*256] | indices[N] (as float) | vectors[N*256]
//
// prep : weight -> bf16 (RTNE), sqr[k] fp32, zero worklist counter
// pass1: phase A: bf16 MFMA approx scores -> per-row min (registers only)
//        phase B: recompute scores, emit codes with s <= rmin+MARGIN into
//        worklist (lives in out's values region; pass3 overwrites).
//        Also inits cand[] = ~0.
// pass2: one wave per candidate: exact fp32 dot, lanes span D (coalesced);
//        lexicographic (score,idx) u64 atomicMin == np.argmin tie-break.
// pass3: gather weight[idx] -> values & vectors, write indices.
//
// Margin proof: |approx-exact| per score <= 2*2^-8*sum|a_i b_i| <~ 2 (5-sigma);
// candidate test needs margin >= 2*err ~ 4; MARGIN=12 -> 3x slack.

constexpr int N_TOK = 65536;
constexpr int KC    = 1024;
constexpr int D     = 256;

constexpr size_t IDX_OFF = (size_t)N_TOK * D;   // 16777216 floats
constexpr size_t VEC_OFF = IDX_OFF + N_TOK;     // 16842752 floats
constexpr int    WL_CAP  = 16777216;            // worklist slots in values region

#define MARGIN 12.0f

typedef __attribute__((ext_vector_type(8))) short bf16x8;
typedef __attribute__((ext_vector_type(4))) float f32x4;

__device__ inline unsigned short f2bf(float x) {
    unsigned int u = __float_as_uint(x);
    unsigned int r = (u + 0x7FFFu + ((u >> 16) & 1u)) >> 16;
    return (unsigned short)r;
}

__device__ inline unsigned int fkey(float f) {
    unsigned int b = __float_as_uint(f);
    return (b & 0x80000000u) ? ~b : (b | 0x80000000u);
}

// ---------------- prep: weight -> bf16, sqr, zero counter ----------------
__global__ __launch_bounds__(64)
void vq_prep(const float* __restrict__ w, unsigned short* __restrict__ wbf,
             float* __restrict__ sqr, int* __restrict__ cnt) {
    const int code = blockIdx.x;
    const int lane = threadIdx.x;
    float4 v = ((const float4*)w)[(size_t)code * 64 + lane];
    float s = v.x * v.x + v.y * v.y + v.z * v.z + v.w * v.w;
#pragma unroll
    for (int off = 32; off >= 1; off >>= 1) s += __shfl_xor(s, off, 64);
    unsigned short* d = wbf + (size_t)code * D + lane * 4;
    d[0] = f2bf(v.x); d[1] = f2bf(v.y); d[2] = f2bf(v.z); d[3] = f2bf(v.w);
    if (lane == 0) sqr[code] = s;
    if (code == 0 && lane == 0) *cnt = 0;
}

// ---------------- pass1: MFMA filter, two-phase fused ----------------
// 512 blocks x 256 thr; wave handles 32 rows (2 row-tiles), all 1024 codes.
__global__ __launch_bounds__(256)
void vq_pass1(const float* __restrict__ input, const unsigned short* __restrict__ wbf,
              const float* __restrict__ sqr, int* __restrict__ wl,
              int* __restrict__ cnt, unsigned long long* __restrict__ cand) {
    const int wave = threadIdx.x >> 6;
    const int lane = threadIdx.x & 63;
    const int col  = lane & 15;
    const int quad = lane >> 4;
    const int row_base = blockIdx.x * 128 + wave * 32;

    if (lane < 32) cand[row_base + lane] = 0xFFFFFFFFFFFFFFFFULL;

    // A fragments: 2 row-tiles x 8 k-tiles, bf16x8 each (64 VGPR)
    bf16x8 a[2][8];
#pragma unroll
    for (int rt = 0; rt < 2; ++rt) {
        const float* ar = input + (size_t)(row_base + rt * 16 + col) * D;
#pragma unroll
        for (int kt = 0; kt < 8; ++kt) {
            const int k0 = kt * 32 + quad * 8;
            float4 f0 = *(const float4*)(ar + k0);
            float4 f1 = *(const float4*)(ar + k0 + 4);
            bf16x8 v;
            v[0] = (short)f2bf(f0.x); v[1] = (short)f2bf(f0.y);
            v[2] = (short)f2bf(f0.z); v[3] = (short)f2bf(f0.w);
            v[4] = (short)f2bf(f1.x); v[5] = (short)f2bf(f1.y);
            v[6] = (short)f2bf(f1.z); v[7] = (short)f2bf(f1.w);
            a[rt][kt] = v;
        }
    }

    // ---- phase A: per-row min over all 1024 codes ----
    float rmin[2][4];
#pragma unroll
    for (int rt = 0; rt < 2; ++rt)
#pragma unroll
        for (int rg = 0; rg < 4; ++rg) rmin[rt][rg] = 3.4e38f;

    for (int t = 0; t < 64; ++t) {          // 64 tiles of 16 codes
        const int c0 = t * 16;
        const unsigned short* wr = wbf + (size_t)(c0 + col) * D + quad * 8;
        bf16x8 b[8];
#pragma unroll
        for (int kt = 0; kt < 8; ++kt)
            b[kt] = *(const bf16x8*)(wr + kt * 32);
        const float sq = sqr[c0 + col];
#pragma unroll
        for (int rt = 0; rt < 2; ++rt) {
            f32x4 acc = {0.f, 0.f, 0.f, 0.f};
#pragma unroll
            for (int kt = 0; kt < 8; ++kt)
                acc = __builtin_amdgcn_mfma_f32_16x16x32_bf16(a[rt][kt], b[kt], acc, 0, 0, 0);
#pragma unroll
            for (int rg = 0; rg < 4; ++rg)
                rmin[rt][rg] = fminf(rmin[rt][rg], sq - 2.0f * acc[rg]);
        }
    }
    // butterfly min over the 16 col-lanes (xor 1,2,4,8 stays within quad)
#pragma unroll
    for (int off = 1; off <= 8; off <<= 1)
#pragma unroll
        for (int rt = 0; rt < 2; ++rt)
#pragma unroll
            for (int rg = 0; rg < 4; ++rg)
                rmin[rt][rg] = fminf(rmin[rt][rg], __shfl_xor(rmin[rt][rg], off, 64));

    // ---- phase B: recompute, emit candidate codes ----
    for (int t = 0; t < 64; ++t) {
        const int c0 = t * 16;
        const unsigned short* wr = wbf + (size_t)(c0 + col) * D + quad * 8;
        bf16x8 b[8];
#pragma unroll
        for (int kt = 0; kt < 8; ++kt)
            b[kt] = *(const bf16x8*)(wr + kt * 32);
        const float sq = sqr[c0 + col];
#pragma unroll
        for (int rt = 0; rt < 2; ++rt) {
            f32x4 acc = {0.f, 0.f, 0.f, 0.f};
#pragma unroll
            for (int kt = 0; kt < 8; ++kt)
                acc = __builtin_amdgcn_mfma_f32_16x16x32_bf16(a[rt][kt], b[kt], acc, 0, 0, 0);
#pragma unroll
            for (int rg = 0; rg < 4; ++rg) {
                const float s = sq - 2.0f * acc[rg];
                const bool flag = (s <= rmin[rt][rg] + MARGIN);
                if (__ballot(flag)) {
                    if (flag) {
                        int pos = atomicAdd(cnt, 1);
                        if (pos < WL_CAP) {
                            int row = row_base + rt * 16 + quad * 4 + rg;
                            wl[pos] = (row << 10) | (c0 + col);
                        }
                    }
                }
            }
        }
    }
}

// ---------------- pass2: coalesced exact fp32 refine ----------------
__global__ __launch_bounds__(256)
void vq_pass2(const float* __restrict__ input, const float* __restrict__ weight,
              const float* __restrict__ sqr, const int* __restrict__ wl,
              const int* __restrict__ cnt, unsigned long long* __restrict__ cand) {
    const int wave = threadIdx.x >> 6;
    const int lane = threadIdx.x & 63;
    const int gw    = blockIdx.x * 4 + wave;
    const int nwave = gridDim.x * 4;
    const int n = min(*cnt, WL_CAP);
    const float4* in4 = (const float4*)input;
    const float4* w4  = (const float4*)weight;

    for (int e = gw; e < n; e += nwave) {
        const int ent  = wl[e];             // wave-uniform
        const int row  = ent >> 10;
        const int code = ent & 1023;
        float4 za = in4[(size_t)row * 64 + lane];   // coalesced 1KB
        float4 wa = w4[(size_t)code * 64 + lane];   // coalesced 1KB
        float s = za.x * wa.x;
        s = fmaf(za.y, wa.y, s);
        s = fmaf(za.z, wa.z, s);
        s = fmaf(za.w, wa.w, s);
#pragma unroll
        for (int off = 32; off >= 1; off >>= 1) s += __shfl_xor(s, off, 64);
        const float score = sqr[code] - 2.0f * s;
        if (lane == 0) {
            unsigned long long key =
                ((unsigned long long)fkey(score) << 32) | (unsigned int)code;
            atomicMin(&cand[row], key);
        }
    }
}

// ---------------- pass3: gather + write outputs ----------------
__global__ __launch_bounds__(256)
void vq_pass3(const float* __restrict__ weight,
              const unsigned long long* __restrict__ cand,
              float* __restrict__ out) {
    __shared__ int fin[64];
    const int tid  = threadIdx.x;
    const int row0 = blockIdx.x * 64;
    if (tid < 64) {
        int idx = (int)(unsigned int)(cand[row0 + tid] & 0xFFFFFFFFULL);
        fin[tid] = idx;
        out[IDX_OFF + row0 + tid] = (float)idx;
    }
    __syncthreads();
    const float4* w4 = (const float4*)weight;
    float4* out4 = (float4*)out;
#pragma unroll
    for (int k = 0; k < 16; ++k) {
        int i = tid + k * 256;
        int r = i >> 6, q = i & 63;
        float4 v = w4[(size_t)fin[r] * 64 + q];
        size_t o = (size_t)(row0 + r) * 64 + q;
        out4[o] = v;                    // values
        out4[VEC_OFF / 4 + o] = v;      // vectors
    }
}

extern "C" void kernel_launch(void* const* d_in, const int* in_sizes, int n_in,
                              void* d_out, int out_size, void* d_ws, size_t ws_size,
                              hipStream_t stream) {
    const float* input  = (const float*)d_in[0];   // [64,32,32,256] f32
    const float* weight = (const float*)d_in[1];   // [1024,256] f32
    float* out = (float*)d_out;

    // ws layout (~1.04 MB)
    unsigned short* wbf = (unsigned short*)d_ws;                            // 512 KB
    float* sqr = (float*)((char*)d_ws + 524288);                            // 4 KB
    int*   cnt = (int*)((char*)d_ws + 528384);                              // 4 B
    unsigned long long* cand = (unsigned long long*)((char*)d_ws + 532480); // 512 KB

    // worklist lives in out's values region (16.7M ints); pass3 overwrites it
    int* wl = (int*)out;

    vq_prep <<<KC, 64, 0, stream>>>(weight, wbf, sqr, cnt);
    vq_pass1<<<N_TOK / 128, 256, 0, stream>>>(input, wbf, sqr, wl, cnt, cand);
    vq_pass2<<<1024, 256, 0, stream>>>(input, weight, sqr, wl, cnt, cand);
    vq_pass3<<<N_TOK / 64, 256, 0, stream>>>(weight, cand, out);
}

// Round 4
// 444.199 us; speedup vs baseline: 5.2705x; 5.2705x over previous
//
#include <hip/hip_runtime.h>

// VQ-VAE nearest-code lookup: MFMA filter (code-granular) + coalesced fp32 refine.
// N=65536 tokens, K=1024 codes, D=256, fp32 in/out.
// out layout (flat f32): values[N*256] | indices[N] (as float) | vectors[N*256]
//
// prep : weight -> bf16 (RTNE), sqr[k] fp32, zero worklist counter
// pass1: phase A: bf16 MFMA approx scores -> per-row min (registers only)
//        phase B: recompute scores, emit codes with s <= rmin+MARGIN into an
//        LDS list (wave-ballot compaction + LDS atomic), flushed to the global
//        worklist with ONE atomicAdd per block (fixes R3's 2ms single-address
//        atomic serialization: ~150K global RMWs -> 512).
// pass2: quarter-wave (16 lanes) per candidate: exact fp32 dot, coalesced;
//        lexicographic (score,idx) u64 atomicMin == np.argmin tie-break.
// pass3: gather weight[idx] -> values & vectors, write indices.
//
// Margin proof: |approx-exact| per score <= 2*2^-9*2*sum|a_i b_i| ~ 1.3 typ,
// <2.5 tail; candidate test needs MARGIN >= 2*err ~ 5; MARGIN=12 -> 2.4x slack.

constexpr int N_TOK = 65536;
constexpr int KC    = 1024;
constexpr int D     = 256;

constexpr size_t IDX_OFF = (size_t)N_TOK * D;   // 16777216 floats
constexpr size_t VEC_OFF = IDX_OFF + N_TOK;     // 16842752 floats
constexpr int    WL_CAP  = 16777216;            // worklist slots in values region

#define MARGIN 12.0f

typedef __attribute__((ext_vector_type(8))) short bf16x8;
typedef __attribute__((ext_vector_type(4))) float f32x4;

__device__ inline unsigned short f2bf(float x) {
    unsigned int u = __float_as_uint(x);
    unsigned int r = (u + 0x7FFFu + ((u >> 16) & 1u)) >> 16;
    return (unsigned short)r;
}

__device__ inline unsigned int fkey(float f) {
    unsigned int b = __float_as_uint(f);
    return (b & 0x80000000u) ? ~b : (b | 0x80000000u);
}

// ---------------- prep: weight -> bf16, sqr, zero counter ----------------
__global__ __launch_bounds__(64)
void vq_prep(const float* __restrict__ w, unsigned short* __restrict__ wbf,
             float* __restrict__ sqr, int* __restrict__ cnt) {
    const int code = blockIdx.x;
    const int lane = threadIdx.x;
    float4 v = ((const float4*)w)[(size_t)code * 64 + lane];
    float s = v.x * v.x + v.y * v.y + v.z * v.z + v.w * v.w;
#pragma unroll
    for (int off = 32; off >= 1; off >>= 1) s += __shfl_xor(s, off, 64);
    unsigned short* d = wbf + (size_t)code * D + lane * 4;
    d[0] = f2bf(v.x); d[1] = f2bf(v.y); d[2] = f2bf(v.z); d[3] = f2bf(v.w);
    if (lane == 0) sqr[code] = s;
    if (code == 0 && lane == 0) *cnt = 0;
}

// ---------------- pass1: MFMA filter, two-phase fused ----------------
// 512 blocks x 256 thr; wave handles 32 rows (2 row-tiles), all 1024 codes.
__global__ __launch_bounds__(256)
void vq_pass1(const float* __restrict__ input, const unsigned short* __restrict__ wbf,
              const float* __restrict__ sqr, int* __restrict__ wl,
              int* __restrict__ cnt, unsigned long long* __restrict__ cand) {
    constexpr int LCAP = 3072;
    __shared__ int lds_list[LCAP];   // 12 KB
    __shared__ int lcnt;
    __shared__ int gbase;

    const int wave = threadIdx.x >> 6;
    const int lane = threadIdx.x & 63;
    const int col  = lane & 15;
    const int quad = lane >> 4;
    const int row_base = blockIdx.x * 128 + wave * 32;

    if (threadIdx.x == 0) lcnt = 0;
    if (lane < 32) cand[row_base + lane] = 0xFFFFFFFFFFFFFFFFULL;

    // A fragments: 2 row-tiles x 8 k-tiles, bf16x8 each (32 VGPRs)
    bf16x8 a[2][8];
#pragma unroll
    for (int rt = 0; rt < 2; ++rt) {
        const float* ar = input + (size_t)(row_base + rt * 16 + col) * D;
#pragma unroll
        for (int kt = 0; kt < 8; ++kt) {
            const int k0 = kt * 32 + quad * 8;
            float4 f0 = *(const float4*)(ar + k0);
            float4 f1 = *(const float4*)(ar + k0 + 4);
            bf16x8 v;
            v[0] = (short)f2bf(f0.x); v[1] = (short)f2bf(f0.y);
            v[2] = (short)f2bf(f0.z); v[3] = (short)f2bf(f0.w);
            v[4] = (short)f2bf(f1.x); v[5] = (short)f2bf(f1.y);
            v[6] = (short)f2bf(f1.z); v[7] = (short)f2bf(f1.w);
            a[rt][kt] = v;
        }
    }

    // ---- phase A: per-row min over all 1024 codes ----
    float rmin[2][4];
#pragma unroll
    for (int rt = 0; rt < 2; ++rt)
#pragma unroll
        for (int rg = 0; rg < 4; ++rg) rmin[rt][rg] = 3.4e38f;

    for (int t = 0; t < 64; ++t) {          // 64 tiles of 16 codes
        const int c0 = t * 16;
        const unsigned short* wr = wbf + (size_t)(c0 + col) * D + quad * 8;
        bf16x8 b[8];
#pragma unroll
        for (int kt = 0; kt < 8; ++kt)
            b[kt] = *(const bf16x8*)(wr + kt * 32);
        const float sq = sqr[c0 + col];
#pragma unroll
        for (int rt = 0; rt < 2; ++rt) {
            f32x4 acc = {0.f, 0.f, 0.f, 0.f};
#pragma unroll
            for (int kt = 0; kt < 8; ++kt)
                acc = __builtin_amdgcn_mfma_f32_16x16x32_bf16(a[rt][kt], b[kt], acc, 0, 0, 0);
#pragma unroll
            for (int rg = 0; rg < 4; ++rg)
                rmin[rt][rg] = fminf(rmin[rt][rg], sq - 2.0f * acc[rg]);
        }
    }
    // butterfly min over the 16 col-lanes (xor 1,2,4,8 stays within quad)
#pragma unroll
    for (int off = 1; off <= 8; off <<= 1)
#pragma unroll
        for (int rt = 0; rt < 2; ++rt)
#pragma unroll
            for (int rg = 0; rg < 4; ++rg)
                rmin[rt][rg] = fminf(rmin[rt][rg], __shfl_xor(rmin[rt][rg], off, 64));

    __syncthreads();   // lcnt=0 visible before any emission

    // ---- phase B: recompute, emit candidates via LDS aggregation ----
    for (int t = 0; t < 64; ++t) {
        const int c0 = t * 16;
        const unsigned short* wr = wbf + (size_t)(c0 + col) * D + quad * 8;
        bf16x8 b[8];
#pragma unroll
        for (int kt = 0; kt < 8; ++kt)
            b[kt] = *(const bf16x8*)(wr + kt * 32);
        const float sq = sqr[c0 + col];
#pragma unroll
        for (int rt = 0; rt < 2; ++rt) {
            f32x4 acc = {0.f, 0.f, 0.f, 0.f};
#pragma unroll
            for (int kt = 0; kt < 8; ++kt)
                acc = __builtin_amdgcn_mfma_f32_16x16x32_bf16(a[rt][kt], b[kt], acc, 0, 0, 0);
#pragma unroll
            for (int rg = 0; rg < 4; ++rg) {
                const float s = sq - 2.0f * acc[rg];
                const bool flag = (s <= rmin[rt][rg] + MARGIN);
                unsigned long long mask = __ballot(flag);
                if (mask) {
                    const int leader = __builtin_ctzll(mask);
                    const int nact   = __popcll(mask);
                    const int prefix = __popcll(mask & ((1ULL << lane) - 1ULL));
                    int wbase = 0;
                    if (lane == leader) wbase = atomicAdd(&lcnt, nact);
                    wbase = __shfl(wbase, leader, 64);
                    if (flag) {
                        const int row  = row_base + rt * 16 + quad * 4 + rg;
                        const int item = (row << 10) | (c0 + col);
                        const int pos  = wbase + prefix;
                        if (pos < LCAP) {
                            lds_list[pos] = item;
                        } else {                      // rare overflow fallback
                            int g = atomicAdd(cnt, 1);
                            if (g < WL_CAP) wl[g] = item;
                        }
                    }
                }
            }
        }
    }

    // ---- flush: one global reservation per block ----
    __syncthreads();
    const int n = min(lcnt, LCAP);
    if (threadIdx.x == 0) gbase = atomicAdd(cnt, n);
    __syncthreads();
    const int base = gbase;
    for (int i = threadIdx.x; i < n; i += 256) wl[base + i] = lds_list[i];
}

// ---------------- pass2: coalesced exact fp32 refine (16 lanes/cand) ------
__global__ __launch_bounds__(256)
void vq_pass2(const float* __restrict__ input, const float* __restrict__ weight,
              const float* __restrict__ sqr, const int* __restrict__ wl,
              const int* __restrict__ cnt, unsigned long long* __restrict__ cand) {
    const int sw  = threadIdx.x >> 4;       // 16 sub-waves per block
    const int sl  = threadIdx.x & 15;
    const int gsw = blockIdx.x * 16 + sw;
    const int nsw = gridDim.x * 16;
    const int n   = min(*cnt, WL_CAP);
    const float4* in4 = (const float4*)input;
    const float4* w4  = (const float4*)weight;

    for (int e = gsw; e < n; e += nsw) {
        const int ent  = wl[e];             // sub-wave-uniform (broadcast)
        const int row  = ent >> 10;
        const int code = ent & 1023;
        const float4* zr = in4 + (size_t)row * 64;
        const float4* wr = w4 + (size_t)code * 64;
        float s = 0.f;
#pragma unroll
        for (int j = 0; j < 4; ++j) {       // lane sl covers q = sl + 16*j
            float4 za = zr[sl + 16 * j];
            float4 wa = wr[sl + 16 * j];
            s = fmaf(za.x, wa.x, s);
            s = fmaf(za.y, wa.y, s);
            s = fmaf(za.z, wa.z, s);
            s = fmaf(za.w, wa.w, s);
        }
#pragma unroll
        for (int off = 1; off <= 8; off <<= 1) s += __shfl_xor(s, off, 16);
        if (sl == 0) {
            const float score = sqr[code] - 2.0f * s;
            unsigned long long key =
                ((unsigned long long)fkey(score) << 32) | (unsigned int)code;
            atomicMin(&cand[row], key);
        }
    }
}

// ---------------- pass3: gather + write outputs ----------------
__global__ __launch_bounds__(256)
void vq_pass3(const float* __restrict__ weight,
              const unsigned long long* __restrict__ cand,
              float* __restrict__ out) {
    __shared__ int fin[64];
    const int tid  = threadIdx.x;
    const int row0 = blockIdx.x * 64;
    if (tid < 64) {
        int idx = (int)(unsigned int)(cand[row0 + tid] & 0xFFFFFFFFULL);
        fin[tid] = idx;
        out[IDX_OFF + row0 + tid] = (float)idx;
    }
    __syncthreads();
    const float4* w4 = (const float4*)weight;
    float4* out4 = (float4*)out;
#pragma unroll
    for (int k = 0; k < 16; ++k) {
        int i = tid + k * 256;
        int r = i >> 6, q = i & 63;
        float4 v = w4[(size_t)fin[r] * 64 + q];
        size_t o = (size_t)(row0 + r) * 64 + q;
        out4[o] = v;                    // values
        out4[VEC_OFF / 4 + o] = v;      // vectors
    }
}

extern "C" void kernel_launch(void* const* d_in, const int* in_sizes, int n_in,
                              void* d_out, int out_size, void* d_ws, size_t ws_size,
                              hipStream_t stream) {
    const float* input  = (const float*)d_in[0];   // [64,32,32,256] f32
    const float* weight = (const float*)d_in[1];   // [1024,256] f32
    float* out = (float*)d_out;

    // ws layout (~1.04 MB)
    unsigned short* wbf = (unsigned short*)d_ws;                            // 512 KB
    float* sqr = (float*)((char*)d_ws + 524288);                            // 4 KB
    int*   cnt = (int*)((char*)d_ws + 528384);                              // 4 B
    unsigned long long* cand = (unsigned long long*)((char*)d_ws + 532480); // 512 KB

    // worklist lives in out's values region (16.7M ints); pass3 overwrites it
    int* wl = (int*)out;

    vq_prep <<<KC, 64, 0, stream>>>(weight, wbf, sqr, cnt);
    vq_pass1<<<N_TOK / 128, 256, 0, stream>>>(input, wbf, sqr, wl, cnt, cand);
    vq_pass2<<<1024, 256, 0, stream>>>(input, weight, sqr, wl, cnt, cand);
    vq_pass3<<<N_TOK / 64, 256, 0, stream>>>(weight, cand, out);
}